// Round 4
// baseline (9772.215 us; speedup 1.0000x reference)
//
#include <hip/hip_runtime.h>
#include <math.h>

// Problem constants
#define N_ROWS 32768      // B*H*W = 8*64*64
#define K_CODES 4096
#define D_DIM 256
#define HW 4096           // H*W
#define CHW 1048576       // C*H*W = 256*4096

// Output layout (float element offsets): loss(1) | quantized(8388608) | perplexity(1)
//                                        | encodings(32768*4096) | idx(32768)
#define OFF_LOSS  0
#define OFF_QUANT 1ULL
#define OFF_PERP  8388609ULL
#define OFF_ENC   8388610ULL
#define OFF_IDX   142606338ULL

// Workspace layout (float element offsets)
#define WS_RN   0           // 32768 row norms
#define WS_EN   32768       // 4096 code norms
#define WS_KEY  36864       // 32768 x u64 keys (d_bits<<32|code)
#define WS_CNT  102400      // 4096 uint counts
#define WS_LOSS 106496      // 1 double
#define WS_CCNT 106498      // candidate counter (u32)
#define WS_CAND 106504      // candidate list, CAP u32
#define CAP     2097152
#define WS_CBF  2203656     // codebook bf16 (1M shorts = 524288 floats)
#define WS_NEED_BYTES ((2203656ULL + 524288ULL) * 4ULL)   // ~10.9 MB

#define MARGIN 2.0e-3f      // >= 2B+2rho (~6.6e-4 worst case): 3x headroom

typedef short bf16x8 __attribute__((ext_vector_type(8)));
typedef float f32x4 __attribute__((ext_vector_type(4)));

// fp32 -> bf16 RNE
__device__ __forceinline__ unsigned short f2bf(float f) {
  unsigned u = __float_as_uint(f);
  unsigned r = u + 0x7FFFu + ((u >> 16) & 1u);
  return (unsigned short)(r >> 16);
}

// numpy pairwise_sum replica for 128 squared elements (must stay bit-identical).
__device__ __forceinline__ float pairwise_sq_128(const float* __restrict__ p, int stride) {
  float r[8];
#pragma unroll
  for (int j = 0; j < 8; ++j) { float v = p[(size_t)j * stride]; r[j] = v * v; }
#pragma unroll
  for (int g = 1; g < 16; ++g) {
#pragma unroll
    for (int j = 0; j < 8; ++j) { float v = p[(size_t)(g * 8 + j) * stride]; r[j] += v * v; }
  }
  return ((r[0] + r[1]) + (r[2] + r[3])) + ((r[4] + r[5]) + (r[6] + r[7]));
}

__global__ void rownorm_k(const float* __restrict__ z, float* __restrict__ rn) {
  int row = blockIdx.x * 256 + threadIdx.x;
  const float* p = z + (size_t)(row >> 12) * CHW + (row & (HW - 1));
  rn[row] = pairwise_sq_128(p, HW) + pairwise_sq_128(p + (size_t)128 * HW, HW);
}

__global__ void enorm_k(const float* __restrict__ cb, float* __restrict__ en) {
  int k = blockIdx.x * 256 + threadIdx.x;
  const float* p = cb + (size_t)k * D_DIM;
  en[k] = pairwise_sq_128(p, 1) + pairwise_sq_128(p + 128, 1);
}

// Pre-convert codebook to bf16 (RNE), once.
__global__ void cbbf_k(const float* __restrict__ cb, unsigned short* __restrict__ cbf) {
  int i = (blockIdx.x * 256 + threadIdx.x) * 4;
  float4 v = *(const float4*)(cb + i);
  unsigned d0 = f2bf(v.x) | ((unsigned)f2bf(v.y) << 16);
  unsigned d1 = f2bf(v.z) | ((unsigned)f2bf(v.w) << 16);
  *(int2*)(cbf + i) = make_int2((int)d0, (int)d1);
}

// MFMA candidate filter: approx score s = en - 2*dot_bf16; per-lane running
// threshold (primed on first tile) emits candidates within MARGIN of row min.
// Grid: (N_ROWS/64) * 2 blocks; block = 64 rows x 2048 codes (16 tiles + prime).
__global__ __launch_bounds__(256, 3) void mfma_filter_k(
    const float* __restrict__ z, const unsigned short* __restrict__ cbf,
    const float* __restrict__ en,
    unsigned int* __restrict__ cand, unsigned int* __restrict__ cnt) {
  __shared__ short ASw[4 * 8 * 64 * 8];   // [rt][ks][lane][8] bf16 : 32 KB
  __shared__ short BSw[8 * 64 * 8];       // [ct][lane][8] bf16 : 8 KB

  const int tid = threadIdx.x;
  const int lane = tid & 63;
  const int w = tid >> 6;                 // wave id = row-tile rt
  const int row_base = (blockIdx.x >> 1) * 64;
  const int q = blockIdx.x & 1;           // code half: tiles q*16 .. q*16+15
  const float* zb = z + (size_t)(row_base >> 12) * CHW + (row_base & (HW - 1));

  // ---- Stage A: 64 rows x 256 dims, fp32->bf16, swizzled to A-frag order ----
  {
    int f4 = tid & 15;
    int r0 = f4 * 4;
#pragma unroll
    for (int it = 0; it < 2; ++it) {
      int c_oct = (tid >> 4) + it * 16;   // 8-dim octet 0..31
      float4 v[8];
#pragma unroll
      for (int j = 0; j < 8; ++j)
        v[j] = *(const float4*)(zb + (size_t)(c_oct * 8 + j) * HW + r0);
      int s = c_oct >> 2, g = c_oct & 3;
#pragma unroll
      for (int i = 0; i < 4; ++i) {
        int r = r0 + i, rt = r >> 4, m = r & 15;
        int dw[4];
#pragma unroll
        for (int k = 0; k < 4; ++k) {
          unsigned lo = f2bf(((const float*)&v[2 * k])[i]);
          unsigned hi = f2bf(((const float*)&v[2 * k + 1])[i]);
          dw[k] = (int)(lo | (hi << 16));
        }
        *(int4*)&ASw[(((rt * 8 + s) * 64) + g * 16 + m) * 8] =
            make_int4(dw[0], dw[1], dw[2], dw[3]);
      }
    }
  }

  float thM[4] = {3.4e38f, 3.4e38f, 3.4e38f, 3.4e38f};  // running row-min + M

  for (int tt = 0; tt <= 16; ++tt) {
    const int prime = (tt == 0);
    const int tile = q * 16 + (prime ? 0 : tt - 1);

    f32x4 acc[8];
#pragma unroll
    for (int ct = 0; ct < 8; ++ct) acc[ct] = (f32x4){0.f, 0.f, 0.f, 0.f};

    for (int ks = 0; ks < 8; ++ks) {
      __syncthreads();   // protect BSw reuse from previous ks
      // Stage B tile (128 codes x 32 dims) from bf16 codebook: pure b128 copy.
#pragma unroll
      for (int it = 0; it < 2; ++it) {
        int n = tid & 127;
        int g = (tid >> 7) + 2 * it;
        int4 v = *(const int4*)(cbf + (size_t)(tile * 128 + n) * 256 + ks * 32 + g * 8);
        *(int4*)&BSw[(((n >> 4) * 64) + g * 16 + (n & 15)) * 8] = v;
      }
      __syncthreads();
      bf16x8 a = *(const bf16x8*)&ASw[((w * 8 + ks) * 64 + lane) * 8];
#pragma unroll
      for (int ct = 0; ct < 8; ++ct) {
        bf16x8 b = *(const bf16x8*)&BSw[(ct * 64 + lane) * 8];
        acc[ct] = __builtin_amdgcn_mfma_f32_16x16x32_bf16(a, b, acc[ct], 0, 0, 0);
      }
    }

    // Scores + emission + per-tile min.
    float tmin[4] = {3.4e38f, 3.4e38f, 3.4e38f, 3.4e38f};
#pragma unroll
    for (int ct = 0; ct < 8; ++ct) {
      int code = tile * 128 + ct * 16 + (lane & 15);
      float ev = en[code];
#pragma unroll
      for (int r = 0; r < 4; ++r) {
        float s = ev - 2.0f * acc[ct][r];
        if (!prime && s <= thM[r]) {
          unsigned row = row_base + w * 16 + (lane >> 4) * 4 + r;
          unsigned idx = atomicAdd(cnt, 1u);
          if (idx < CAP) cand[idx] = (row << 12) | (unsigned)code;
        }
        tmin[r] = fminf(tmin[r], s);
      }
    }
#pragma unroll
    for (int r = 0; r < 4; ++r) {   // min over the 16-lane column group
      float v = tmin[r];
      v = fminf(v, __shfl_xor(v, 1));
      v = fminf(v, __shfl_xor(v, 2));
      v = fminf(v, __shfl_xor(v, 4));
      v = fminf(v, __shfl_xor(v, 8));
      thM[r] = fminf(thM[r], v + MARGIN);
    }
  }
}

// Exact re-verify: replay the r3 fp32 fmaf chain (bit-identical) per candidate.
__global__ void verify_k(const float* __restrict__ z, const float* __restrict__ cb,
                         const float* __restrict__ rn, const float* __restrict__ en,
                         const unsigned int* __restrict__ cand,
                         const unsigned int* __restrict__ cnt,
                         unsigned long long* __restrict__ key) {
  unsigned total = *cnt; if (total > CAP) total = CAP;
  for (unsigned i = blockIdx.x * 256 + threadIdx.x; i < total; i += gridDim.x * 256) {
    unsigned pc = cand[i];
    unsigned row = pc >> 12, code = pc & 4095u;
    const float* x = z + (size_t)(row >> 12) * CHW + (row & (HW - 1));
    const float* e = cb + (size_t)code * D_DIM;
    float acc = 0.0f;
#pragma unroll 8
    for (int c = 0; c < D_DIM; ++c) acc = fmaf(x[(size_t)c * HW], e[c], acc);
    float d = (rn[row] + en[code]) - 2.0f * acc;   // reference rounding order
    unsigned long long k64 = ((unsigned long long)__float_as_uint(d) << 32) | code;
    atomicMin(&key[row], k64);
  }
}

// ---------- Fallback fp32 argmin (r3, known-passing) ----------
#define BM 128
#define BN 128
#define BK 32
#define KQ 1024
#define ES_S 36
__global__ __launch_bounds__(256, 3) void argmin_fb(
    const float* __restrict__ z, const float* __restrict__ cb,
    const float* __restrict__ rn, const float* __restrict__ en,
    unsigned long long* __restrict__ key) {
  __shared__ union {
    struct { float Xs[BK * BM]; float Es[BN * ES_S]; } s;
    struct { float rv[BM * 16]; int ri[BM * 16]; } r;
  } sh;
  const int tid = threadIdx.x;
  const int tx = tid & 15, ty = tid >> 4;
  const int row_base = (blockIdx.x >> 2) * BM;
  const int q = blockIdx.x & 3;
  const float* zb = z + (size_t)(row_base >> 12) * CHW + (row_base & (HW - 1));
  float rnv[8];
#pragma unroll
  for (int i = 0; i < 8; ++i) rnv[i] = rn[row_base + ty * 8 + i];
  float bestV[8]; int bestI[8];
#pragma unroll
  for (int i = 0; i < 8; ++i) { bestV[i] = 3.4e38f; bestI[i] = 0; }
  for (int t0 = q * KQ; t0 < q * KQ + KQ; t0 += BN) {
    float acc[8][8];
#pragma unroll
    for (int i = 0; i < 8; ++i)
#pragma unroll
      for (int j = 0; j < 8; ++j) acc[i][j] = 0.0f;
    for (int kb = 0; kb < D_DIM; kb += BK) {
      __syncthreads();
#pragma unroll
      for (int k = 0; k < 4; ++k) {
        int l4 = tid + k * 256, cl = l4 >> 5, ro = (l4 & 31) << 2;
        *(float4*)&sh.s.Xs[cl * BM + ro] = *(const float4*)(zb + (size_t)(kb + cl) * HW + ro);
      }
#pragma unroll
      for (int k = 0; k < 4; ++k) {
        int l4 = tid + k * 256, kl = l4 >> 3, cq = (l4 & 7) << 2;
        *(float4*)&sh.s.Es[kl * ES_S + cq] =
            *(const float4*)(cb + (size_t)(t0 + kl) * D_DIM + kb + cq);
      }
      __syncthreads();
#pragma unroll
      for (int c4 = 0; c4 < BK / 4; ++c4) {
        float4 ef[8];
#pragma unroll
        for (int j = 0; j < 8; ++j)
          ef[j] = *(const float4*)&sh.s.Es[(tx + 16 * j) * ES_S + c4 * 4];
#pragma unroll
        for (int cc = 0; cc < 4; ++cc) {
          int c = c4 * 4 + cc;
          float4 xa = *(const float4*)&sh.s.Xs[c * BM + ty * 8];
          float4 xb = *(const float4*)&sh.s.Xs[c * BM + ty * 8 + 4];
          float xv[8] = {xa.x, xa.y, xa.z, xa.w, xb.x, xb.y, xb.z, xb.w};
          float evv[8] = {((const float*)&ef[0])[cc], ((const float*)&ef[1])[cc],
                          ((const float*)&ef[2])[cc], ((const float*)&ef[3])[cc],
                          ((const float*)&ef[4])[cc], ((const float*)&ef[5])[cc],
                          ((const float*)&ef[6])[cc], ((const float*)&ef[7])[cc]};
#pragma unroll
          for (int i = 0; i < 8; ++i)
#pragma unroll
            for (int j = 0; j < 8; ++j) acc[i][j] = fmaf(xv[i], evv[j], acc[i][j]);
        }
      }
    }
#pragma unroll
    for (int j = 0; j < 8; ++j) {
      int code = t0 + tx + 16 * j;
      float ev = en[code];
#pragma unroll
      for (int i = 0; i < 8; ++i) {
        float d = (rnv[i] + ev) - 2.0f * acc[i][j];
        if (d < bestV[i]) { bestV[i] = d; bestI[i] = code; }
      }
    }
  }
  __syncthreads();
#pragma unroll
  for (int i = 0; i < 8; ++i) {
    sh.r.rv[(ty * 8 + i) * 16 + tx] = bestV[i];
    sh.r.ri[(ty * 8 + i) * 16 + tx] = bestI[i];
  }
  __syncthreads();
  if (tid < BM) {
    float bv = sh.r.rv[tid * 16]; int bi = sh.r.ri[tid * 16];
    for (int t = 1; t < 16; ++t) {
      float v = sh.r.rv[tid * 16 + t]; int ii = sh.r.ri[tid * 16 + t];
      if (v < bv || (v == bv && ii < bi)) { bv = v; bi = ii; }
    }
    unsigned long long k64 = ((unsigned long long)__float_as_uint(bv) << 32) | (unsigned)bi;
    atomicMin(&key[row_base + tid], k64);
  }
}
// ---------- end fallback ----------

__global__ void scatter_k(const unsigned long long* __restrict__ key,
                          unsigned int* __restrict__ counts, float* __restrict__ out) {
  int row = blockIdx.x * 256 + threadIdx.x;
  int bi = (int)(unsigned int)(key[row] & 0xffffffffULL);
  out[OFF_IDX + row] = (float)bi;
  out[OFF_ENC + (size_t)row * K_CODES + bi] = 1.0f;
  atomicAdd(&counts[bi], 1u);
}

__global__ void quant_k(const float* __restrict__ z, const float* __restrict__ cb,
                        const unsigned long long* __restrict__ key, float* __restrict__ out,
                        double* __restrict__ losssum) {
  __shared__ double red[256];
  int bh = blockIdx.x, b = bh >> 6, h = bh & 63;
  int tid = threadIdx.x, w = tid & 63, c0 = tid >> 6;
  int n = (b << 12) + (h << 6) + w;
  int iv = (int)(unsigned int)(key[n] & 0xffffffffULL);
  const float* cbr = cb + (size_t)iv * D_DIM;
  size_t zoff = (size_t)b * CHW + (size_t)(h << 6) + w;
  double s = 0.0;
  for (int c = c0; c < D_DIM; c += 4) {
    float zv = z[zoff + (size_t)c * HW];
    float qv = cbr[c];
    float diff = qv - zv;
    out[OFF_QUANT + zoff + (size_t)c * HW] = zv + diff;   // STE forward rounding
    double dd = (double)qv - (double)zv;
    s += dd * dd;
  }
  red[tid] = s;
  __syncthreads();
  for (int st = 128; st > 0; st >>= 1) {
    if (tid < st) red[tid] += red[tid + st];
    __syncthreads();
  }
  if (tid == 0) atomicAdd(losssum, red[0]);
}

__global__ void final_k(const unsigned int* __restrict__ counts,
                        const double* __restrict__ losssum, float* __restrict__ out) {
  __shared__ double red[256];
  int tid = threadIdx.x;
  double s = 0.0;
  for (int k = tid; k < K_CODES; k += 256) {
    double p = (double)counts[k] / 32768.0;
    s += p * log(p + 1e-10);
  }
  red[tid] = s;
  __syncthreads();
  for (int st = 128; st > 0; st >>= 1) {
    if (tid < st) red[tid] += red[tid + st];
    __syncthreads();
  }
  if (tid == 0) {
    out[OFF_PERP] = (float)exp(-red[0]);
    out[OFF_LOSS] = (float)(1.25 * losssum[0] / 8388608.0);
  }
}

extern "C" void kernel_launch(void* const* d_in, const int* in_sizes, int n_in,
                              void* d_out, int out_size, void* d_ws, size_t ws_size,
                              hipStream_t stream) {
  (void)in_sizes; (void)n_in; (void)out_size;
  const float* z = (const float*)d_in[0];
  const float* cb = (const float*)d_in[1];
  float* out = (float*)d_out;
  float* ws = (float*)d_ws;

  float* rn = ws + WS_RN;
  float* en = ws + WS_EN;
  unsigned long long* key = (unsigned long long*)(ws + WS_KEY);
  unsigned int* counts = (unsigned int*)(ws + WS_CNT);
  double* losssum = (double*)(ws + WS_LOSS);

  // Common zero/init
  hipMemsetAsync(out + OFF_ENC, 0, (size_t)N_ROWS * K_CODES * sizeof(float), stream);
  hipMemsetAsync(ws + WS_KEY, 0xFF, (size_t)N_ROWS * sizeof(unsigned long long), stream);

  rownorm_k<<<N_ROWS / 256, 256, 0, stream>>>(z, rn);
  enorm_k<<<K_CODES / 256, 256, 0, stream>>>(cb, en);

  if (ws_size >= WS_NEED_BYTES) {
    unsigned int* ccnt = (unsigned int*)(ws + WS_CCNT);
    unsigned int* cand = (unsigned int*)(ws + WS_CAND);
    unsigned short* cbf = (unsigned short*)(ws + WS_CBF);
    hipMemsetAsync(ws + WS_CNT, 0, (WS_CAND - WS_CNT) * sizeof(float), stream);
    cbbf_k<<<(K_CODES * D_DIM / 4) / 256, 256, 0, stream>>>(cb, cbf);
    mfma_filter_k<<<(N_ROWS / 64) * 2, 256, 0, stream>>>(z, cbf, en, cand, ccnt);
    verify_k<<<1024, 256, 0, stream>>>(z, cb, rn, en, cand, ccnt, key);
  } else {
    hipMemsetAsync(ws + WS_CNT, 0, K_CODES * sizeof(unsigned int) + 2 * sizeof(double), stream);
    argmin_fb<<<(N_ROWS / BM) * 4, 256, 0, stream>>>(z, cb, rn, en, key);
  }

  scatter_k<<<N_ROWS / 256, 256, 0, stream>>>(key, counts, out);
  quant_k<<<512, 256, 0, stream>>>(z, cb, key, out, losssum);
  final_k<<<1, 256, 0, stream>>>(counts, losssum, out);
}

// Round 5
// 1095.836 us; speedup vs baseline: 8.9176x; 8.9176x over previous
//
#include <hip/hip_runtime.h>
#include <math.h>

// Problem constants
#define N_ROWS 32768      // B*H*W = 8*64*64
#define K_CODES 4096
#define D_DIM 256
#define HW 4096           // H*W
#define CHW 1048576       // C*H*W = 256*4096

// Output layout (float element offsets): loss(1) | quantized(8388608) | perplexity(1)
//                                        | encodings(32768*4096) | idx(32768)
#define OFF_LOSS  0
#define OFF_QUANT 1ULL
#define OFF_PERP  8388609ULL
#define OFF_ENC   8388610ULL
#define OFF_IDX   142606338ULL

// Workspace layout (float element offsets)
#define WS_RN   0           // 32768 row norms
#define WS_EN   32768       // 4096 code norms
#define WS_KEY  36864       // 32768 x u64 keys (d_bits<<32|code)
#define WS_CNT  102400      // 4096 uint counts
#define WS_LOSS 106496      // 1 double
#define WS_CCNT 106498      // global candidate counter (u32) + pad
#define WS_THR  106504      // 32768 per-row bf16-score min
#define WS_CAND 139272      // candidate list, CAP u32
#define CAP     1048576
#define WS_CBF  1187848     // codebook bf16 (1M shorts = 524288 floats); 16B aligned
#define WS_NEED_BYTES ((1187848ULL + 524288ULL) * 4ULL)   // ~6.9 MB (proven available in r4)

#define MARGIN 1.5e-3f      // worst-case |approx-exact| <= 2.8e-4 : 5x headroom
#define LBUF_N 1536         // per-block LDS emission buffer

typedef short bf16x8 __attribute__((ext_vector_type(8)));
typedef float f32x4 __attribute__((ext_vector_type(4)));

// fp32 -> bf16 RNE
__device__ __forceinline__ unsigned short f2bf(float f) {
  unsigned u = __float_as_uint(f);
  unsigned r = u + 0x7FFFu + ((u >> 16) & 1u);
  return (unsigned short)(r >> 16);
}

// numpy pairwise_sum replica for 128 squared elements (must stay bit-identical).
__device__ __forceinline__ float pairwise_sq_128(const float* __restrict__ p, int stride) {
  float r[8];
#pragma unroll
  for (int j = 0; j < 8; ++j) { float v = p[(size_t)j * stride]; r[j] = v * v; }
#pragma unroll
  for (int g = 1; g < 16; ++g) {
#pragma unroll
    for (int j = 0; j < 8; ++j) { float v = p[(size_t)(g * 8 + j) * stride]; r[j] += v * v; }
  }
  return ((r[0] + r[1]) + (r[2] + r[3])) + ((r[4] + r[5]) + (r[6] + r[7]));
}

__global__ void rownorm_k(const float* __restrict__ z, float* __restrict__ rn) {
  int row = blockIdx.x * 256 + threadIdx.x;
  const float* p = z + (size_t)(row >> 12) * CHW + (row & (HW - 1));
  rn[row] = pairwise_sq_128(p, HW) + pairwise_sq_128(p + (size_t)128 * HW, HW);
}

__global__ void enorm_k(const float* __restrict__ cb, float* __restrict__ en) {
  int k = blockIdx.x * 256 + threadIdx.x;
  const float* p = cb + (size_t)k * D_DIM;
  en[k] = pairwise_sq_128(p, 1) + pairwise_sq_128(p + 128, 1);
}

__global__ void cbbf_k(const float* __restrict__ cb, unsigned short* __restrict__ cbf) {
  int i = (blockIdx.x * 256 + threadIdx.x) * 4;
  float4 v = *(const float4*)(cb + i);
  unsigned d0 = f2bf(v.x) | ((unsigned)f2bf(v.y) << 16);
  unsigned d1 = f2bf(v.z) | ((unsigned)f2bf(v.w) << 16);
  *(int2*)(cbf + i) = make_int2((int)d0, (int)d1);
}

// Two-pass MFMA filter. Block = 64 rows x ALL 4096 codes (32 tiles of 128).
// EMIT=0: compute per-row min of approx score s = en - 2*dot_bf16, plain store.
// EMIT=1: re-scan (bit-identical), emit (row,code) with s <= rowmin+MARGIN into
//         a per-block LDS buffer; one global atomicAdd per block at flush.
template <int EMIT>
__global__ __launch_bounds__(256, 2) void pass_k(
    const float* __restrict__ z, const unsigned short* __restrict__ cbf,
    const float* __restrict__ en, float* __restrict__ rowmin,
    unsigned int* __restrict__ cand, unsigned int* __restrict__ gcnt) {
  __shared__ short ASw[4 * 8 * 64 * 8];   // [rt][ks][lane][8] bf16 : 32 KB
  __shared__ short BSw[8 * 64 * 8];       // [ct][lane][8] bf16 : 8 KB
  __shared__ unsigned int lbuf[LBUF_N];   // 6 KB (EMIT only)
  __shared__ unsigned int lcnt, gbase;

  const int tid = threadIdx.x;
  const int lane = tid & 63;
  const int w = tid >> 6;                 // wave id = row-tile rt
  const int row_base = blockIdx.x * 64;
  const float* zb = z + (size_t)(row_base >> 12) * CHW + (row_base & (HW - 1));

  if (EMIT && tid == 0) lcnt = 0;

  // ---- Stage A: 64 rows x 256 dims, fp32->bf16, swizzled to A-frag order ----
  // (verbatim from r4 — correctness-proven)
  {
    int f4 = tid & 15;
    int r0 = f4 * 4;
#pragma unroll
    for (int it = 0; it < 2; ++it) {
      int c_oct = (tid >> 4) + it * 16;   // 8-dim octet 0..31
      float4 v[8];
#pragma unroll
      for (int j = 0; j < 8; ++j)
        v[j] = *(const float4*)(zb + (size_t)(c_oct * 8 + j) * HW + r0);
      int s = c_oct >> 2, g = c_oct & 3;
#pragma unroll
      for (int i = 0; i < 4; ++i) {
        int r = r0 + i, rt = r >> 4, m = r & 15;
        int dw[4];
#pragma unroll
        for (int k = 0; k < 4; ++k) {
          unsigned lo = f2bf(((const float*)&v[2 * k])[i]);
          unsigned hi = f2bf(((const float*)&v[2 * k + 1])[i]);
          dw[k] = (int)(lo | (hi << 16));
        }
        *(int4*)&ASw[(((rt * 8 + s) * 64) + g * 16 + m) * 8] =
            make_int4(dw[0], dw[1], dw[2], dw[3]);
      }
    }
  }

  float thr[4];
  float rmin[4] = {3.4e38f, 3.4e38f, 3.4e38f, 3.4e38f};
  if (EMIT) {
#pragma unroll
    for (int r = 0; r < 4; ++r)
      thr[r] = rowmin[row_base + w * 16 + (lane >> 4) * 4 + r] + MARGIN;
  }

  for (int tile = 0; tile < 32; ++tile) {
    f32x4 acc[8];
#pragma unroll
    for (int ct = 0; ct < 8; ++ct) acc[ct] = (f32x4){0.f, 0.f, 0.f, 0.f};

    for (int ks = 0; ks < 8; ++ks) {
      __syncthreads();   // covers A staging (first iter) and BSw reuse
#pragma unroll
      for (int it = 0; it < 2; ++it) {
        int n = tid & 127;
        int g = (tid >> 7) + 2 * it;
        int4 v = *(const int4*)(cbf + (size_t)(tile * 128 + n) * 256 + ks * 32 + g * 8);
        *(int4*)&BSw[(((n >> 4) * 64) + g * 16 + (n & 15)) * 8] = v;
      }
      __syncthreads();
      bf16x8 a = *(const bf16x8*)&ASw[((w * 8 + ks) * 64 + lane) * 8];
#pragma unroll
      for (int ct = 0; ct < 8; ++ct) {
        bf16x8 b = *(const bf16x8*)&BSw[(ct * 64 + lane) * 8];
        acc[ct] = __builtin_amdgcn_mfma_f32_16x16x32_bf16(a, b, acc[ct], 0, 0, 0);
      }
    }

#pragma unroll
    for (int ct = 0; ct < 8; ++ct) {
      int code = tile * 128 + ct * 16 + (lane & 15);
      float ev = en[code];
#pragma unroll
      for (int r = 0; r < 4; ++r) {
        float s = ev - 2.0f * acc[ct][r];
        if (EMIT) {
          if (s <= thr[r]) {
            unsigned row = row_base + w * 16 + (lane >> 4) * 4 + r;
            unsigned pc = (row << 12) | (unsigned)code;
            unsigned pos = atomicAdd(&lcnt, 1u);       // LDS atomic: block-local
            if (pos < LBUF_N) lbuf[pos] = pc;
            else { unsigned g = atomicAdd(gcnt, 1u); if (g < CAP) cand[g] = pc; }
          }
        } else {
          rmin[r] = fminf(rmin[r], s);
        }
      }
    }
  }

  if (!EMIT) {
    // Reduce over the 16 column-lanes; one plain store per row (block owns row).
#pragma unroll
    for (int r = 0; r < 4; ++r) {
      float v = rmin[r];
      v = fminf(v, __shfl_xor(v, 1));
      v = fminf(v, __shfl_xor(v, 2));
      v = fminf(v, __shfl_xor(v, 4));
      v = fminf(v, __shfl_xor(v, 8));
      if ((lane & 15) == 0)
        rowmin[row_base + w * 16 + (lane >> 4) * 4 + r] = v;
    }
  } else {
    // Flush LDS buffer: ONE global atomic per block, then coalesced copy.
    __syncthreads();
    unsigned n = lcnt; if (n > LBUF_N) n = LBUF_N;
    if (tid == 0) gbase = atomicAdd(gcnt, n);
    __syncthreads();
    for (unsigned i = tid; i < n; i += 256) {
      unsigned g = gbase + i;
      if (g < CAP) cand[g] = lbuf[i];
    }
  }
}

// Exact re-verify: replay the exact fp32 fmaf chain (bit-identical to fallback).
__global__ void verify_k(const float* __restrict__ z, const float* __restrict__ cb,
                         const float* __restrict__ rn, const float* __restrict__ en,
                         const unsigned int* __restrict__ cand,
                         const unsigned int* __restrict__ cnt,
                         unsigned long long* __restrict__ key) {
  unsigned total = *cnt; if (total > CAP) total = CAP;
  for (unsigned i = blockIdx.x * 256 + threadIdx.x; i < total; i += gridDim.x * 256) {
    unsigned pc = cand[i];
    unsigned row = pc >> 12, code = pc & 4095u;
    const float* x = z + (size_t)(row >> 12) * CHW + (row & (HW - 1));
    const float* e = cb + (size_t)code * D_DIM;
    float acc = 0.0f;
#pragma unroll 8
    for (int c = 0; c < D_DIM; ++c) acc = fmaf(x[(size_t)c * HW], e[c], acc);
    float d = (rn[row] + en[code]) - 2.0f * acc;   // reference rounding order
    unsigned long long k64 = ((unsigned long long)__float_as_uint(d) << 32) | code;
    atomicMin(&key[row], k64);
  }
}

// ---------- Fallback fp32 argmin (r3, known-passing) ----------
#define BM 128
#define BN 128
#define BK 32
#define KQ 1024
#define ES_S 36
__global__ __launch_bounds__(256, 3) void argmin_fb(
    const float* __restrict__ z, const float* __restrict__ cb,
    const float* __restrict__ rn, const float* __restrict__ en,
    unsigned long long* __restrict__ key) {
  __shared__ union {
    struct { float Xs[BK * BM]; float Es[BN * ES_S]; } s;
    struct { float rv[BM * 16]; int ri[BM * 16]; } r;
  } sh;
  const int tid = threadIdx.x;
  const int tx = tid & 15, ty = tid >> 4;
  const int row_base = (blockIdx.x >> 2) * BM;
  const int q = blockIdx.x & 3;
  const float* zb = z + (size_t)(row_base >> 12) * CHW + (row_base & (HW - 1));
  float rnv[8];
#pragma unroll
  for (int i = 0; i < 8; ++i) rnv[i] = rn[row_base + ty * 8 + i];
  float bestV[8]; int bestI[8];
#pragma unroll
  for (int i = 0; i < 8; ++i) { bestV[i] = 3.4e38f; bestI[i] = 0; }
  for (int t0 = q * KQ; t0 < q * KQ + KQ; t0 += BN) {
    float acc[8][8];
#pragma unroll
    for (int i = 0; i < 8; ++i)
#pragma unroll
      for (int j = 0; j < 8; ++j) acc[i][j] = 0.0f;
    for (int kb = 0; kb < D_DIM; kb += BK) {
      __syncthreads();
#pragma unroll
      for (int k = 0; k < 4; ++k) {
        int l4 = tid + k * 256, cl = l4 >> 5, ro = (l4 & 31) << 2;
        *(float4*)&sh.s.Xs[cl * BM + ro] = *(const float4*)(zb + (size_t)(kb + cl) * HW + ro);
      }
#pragma unroll
      for (int k = 0; k < 4; ++k) {
        int l4 = tid + k * 256, kl = l4 >> 3, cq = (l4 & 7) << 2;
        *(float4*)&sh.s.Es[kl * ES_S + cq] =
            *(const float4*)(cb + (size_t)(t0 + kl) * D_DIM + kb + cq);
      }
      __syncthreads();
#pragma unroll
      for (int c4 = 0; c4 < BK / 4; ++c4) {
        float4 ef[8];
#pragma unroll
        for (int j = 0; j < 8; ++j)
          ef[j] = *(const float4*)&sh.s.Es[(tx + 16 * j) * ES_S + c4 * 4];
#pragma unroll
        for (int cc = 0; cc < 4; ++cc) {
          int c = c4 * 4 + cc;
          float4 xa = *(const float4*)&sh.s.Xs[c * BM + ty * 8];
          float4 xb = *(const float4*)&sh.s.Xs[c * BM + ty * 8 + 4];
          float xv[8] = {xa.x, xa.y, xa.z, xa.w, xb.x, xb.y, xb.z, xb.w};
          float evv[8] = {((const float*)&ef[0])[cc], ((const float*)&ef[1])[cc],
                          ((const float*)&ef[2])[cc], ((const float*)&ef[3])[cc],
                          ((const float*)&ef[4])[cc], ((const float*)&ef[5])[cc],
                          ((const float*)&ef[6])[cc], ((const float*)&ef[7])[cc]};
#pragma unroll
          for (int i = 0; i < 8; ++i)
#pragma unroll
            for (int j = 0; j < 8; ++j) acc[i][j] = fmaf(xv[i], evv[j], acc[i][j]);
        }
      }
    }
#pragma unroll
    for (int j = 0; j < 8; ++j) {
      int code = t0 + tx + 16 * j;
      float ev = en[code];
#pragma unroll
      for (int i = 0; i < 8; ++i) {
        float d = (rnv[i] + ev) - 2.0f * acc[i][j];
        if (d < bestV[i]) { bestV[i] = d; bestI[i] = code; }
      }
    }
  }
  __syncthreads();
#pragma unroll
  for (int i = 0; i < 8; ++i) {
    sh.r.rv[(ty * 8 + i) * 16 + tx] = bestV[i];
    sh.r.ri[(ty * 8 + i) * 16 + tx] = bestI[i];
  }
  __syncthreads();
  if (tid < BM) {
    float bv = sh.r.rv[tid * 16]; int bi = sh.r.ri[tid * 16];
    for (int t = 1; t < 16; ++t) {
      float v = sh.r.rv[tid * 16 + t]; int ii = sh.r.ri[tid * 16 + t];
      if (v < bv || (v == bv && ii < bi)) { bv = v; bi = ii; }
    }
    unsigned long long k64 = ((unsigned long long)__float_as_uint(bv) << 32) | (unsigned)bi;
    atomicMin(&key[row_base + tid], k64);
  }
}
// ---------- end fallback ----------

__global__ void scatter_k(const unsigned long long* __restrict__ key,
                          unsigned int* __restrict__ counts, float* __restrict__ out) {
  int row = blockIdx.x * 256 + threadIdx.x;
  int bi = (int)(unsigned int)(key[row] & 0xffffffffULL);
  out[OFF_IDX + row] = (float)bi;
  out[OFF_ENC + (size_t)row * K_CODES + bi] = 1.0f;
  atomicAdd(&counts[bi], 1u);
}

__global__ void quant_k(const float* __restrict__ z, const float* __restrict__ cb,
                        const unsigned long long* __restrict__ key, float* __restrict__ out,
                        double* __restrict__ losssum) {
  __shared__ double red[256];
  int bh = blockIdx.x, b = bh >> 6, h = bh & 63;
  int tid = threadIdx.x, w = tid & 63, c0 = tid >> 6;
  int n = (b << 12) + (h << 6) + w;
  int iv = (int)(unsigned int)(key[n] & 0xffffffffULL);
  const float* cbr = cb + (size_t)iv * D_DIM;
  size_t zoff = (size_t)b * CHW + (size_t)(h << 6) + w;
  double s = 0.0;
  for (int c = c0; c < D_DIM; c += 4) {
    float zv = z[zoff + (size_t)c * HW];
    float qv = cbr[c];
    float diff = qv - zv;
    out[OFF_QUANT + zoff + (size_t)c * HW] = zv + diff;   // STE forward rounding
    double dd = (double)qv - (double)zv;
    s += dd * dd;
  }
  red[tid] = s;
  __syncthreads();
  for (int st = 128; st > 0; st >>= 1) {
    if (tid < st) red[tid] += red[tid + st];
    __syncthreads();
  }
  if (tid == 0) atomicAdd(losssum, red[0]);
}

__global__ void final_k(const unsigned int* __restrict__ counts,
                        const double* __restrict__ losssum, float* __restrict__ out) {
  __shared__ double red[256];
  int tid = threadIdx.x;
  double s = 0.0;
  for (int k = tid; k < K_CODES; k += 256) {
    double p = (double)counts[k] / 32768.0;
    s += p * log(p + 1e-10);
  }
  red[tid] = s;
  __syncthreads();
  for (int st = 128; st > 0; st >>= 1) {
    if (tid < st) red[tid] += red[tid + st];
    __syncthreads();
  }
  if (tid == 0) {
    out[OFF_PERP] = (float)exp(-red[0]);
    out[OFF_LOSS] = (float)(1.25 * losssum[0] / 8388608.0);
  }
}

extern "C" void kernel_launch(void* const* d_in, const int* in_sizes, int n_in,
                              void* d_out, int out_size, void* d_ws, size_t ws_size,
                              hipStream_t stream) {
  (void)in_sizes; (void)n_in; (void)out_size;
  const float* z = (const float*)d_in[0];
  const float* cb = (const float*)d_in[1];
  float* out = (float*)d_out;
  float* ws = (float*)d_ws;

  float* rn = ws + WS_RN;
  float* en = ws + WS_EN;
  unsigned long long* key = (unsigned long long*)(ws + WS_KEY);
  unsigned int* counts = (unsigned int*)(ws + WS_CNT);
  double* losssum = (double*)(ws + WS_LOSS);

  hipMemsetAsync(out + OFF_ENC, 0, (size_t)N_ROWS * K_CODES * sizeof(float), stream);
  hipMemsetAsync(ws + WS_KEY, 0xFF, (size_t)N_ROWS * sizeof(unsigned long long), stream);

  rownorm_k<<<N_ROWS / 256, 256, 0, stream>>>(z, rn);
  enorm_k<<<K_CODES / 256, 256, 0, stream>>>(cb, en);

  if (ws_size >= WS_NEED_BYTES) {
    unsigned int* gcnt = (unsigned int*)(ws + WS_CCNT);
    float* rowmin = ws + WS_THR;
    unsigned int* cand = (unsigned int*)(ws + WS_CAND);
    unsigned short* cbf = (unsigned short*)(ws + WS_CBF);
    // zero counts(4096) + loss(2) + gcnt(1) + pad
    hipMemsetAsync(ws + WS_CNT, 0, (WS_THR - WS_CNT) * sizeof(float), stream);
    cbbf_k<<<(K_CODES * D_DIM / 4) / 256, 256, 0, stream>>>(cb, cbf);
    pass_k<0><<<N_ROWS / 64, 256, 0, stream>>>(z, cbf, en, rowmin, cand, gcnt);
    pass_k<1><<<N_ROWS / 64, 256, 0, stream>>>(z, cbf, en, rowmin, cand, gcnt);
    verify_k<<<512, 256, 0, stream>>>(z, cb, rn, en, cand, gcnt, key);
  } else {
    hipMemsetAsync(ws + WS_CNT, 0, K_CODES * sizeof(unsigned int) + 2 * sizeof(double), stream);
    argmin_fb<<<(N_ROWS / BM) * 4, 256, 0, stream>>>(z, cb, rn, en, key);
  }

  scatter_k<<<N_ROWS / 256, 256, 0, stream>>>(key, counts, out);
  quant_k<<<512, 256, 0, stream>>>(z, cb, key, out, losssum);
  final_k<<<1, 256, 0, stream>>>(counts, losssum, out);
}